// Round 2
// baseline (536.551 us; speedup 1.0000x reference)
//
#include <hip/hip_runtime.h>
#include <math.h>

// Problem constants (B=2,S=2048 -> T=4096 tokens)
#define T_TOK 4096
#define H_DIM 1024
#define F_DIM 4096
#define E_NUM 8
#define BK 64
#define KSPLIT 2  // ffn2 split-K (fast path)

typedef __attribute__((ext_vector_type(8))) short bhalf8_t;
typedef __attribute__((ext_vector_type(8))) unsigned short ushort8_t;
typedef __attribute__((ext_vector_type(4))) float f32x4_t;

// fp32 -> bf16 round-to-nearest-even
__device__ __forceinline__ unsigned short f2bf(float f) {
  unsigned int u = __float_as_uint(f);
  return (unsigned short)((u + 0x7fffu + ((u >> 16) & 1u)) >> 16);
}

// async global->LDS, 16B per lane. LDS dest = wave-uniform base + lane*16.
__device__ __forceinline__ void gload16(const void* g, void* l) {
  __builtin_amdgcn_global_load_lds(
      (const __attribute__((address_space(1))) unsigned int*)g,
      (__attribute__((address_space(3))) unsigned int*)l, 16, 0, 0);
}

// ---- fp32 [K][N] tile -> bf16 [N][K] (expert offset applied by caller) ----
__device__ __forceinline__ void transpose_dev(const float* __restrict__ src,
                                              unsigned short* __restrict__ dst,
                                              int K, int N, int bx, int by, void* sm_) {
  float(*tile)[65] = (float(*)[65])sm_;  // 64x65 fp32, +1 pad
  const int n0 = bx * 64;
  const int k0 = by * 64;
  const int l = threadIdx.x;
  const int lr = l >> 4;          // 0..15 (k-row within pass)
  const int lc = (l & 15) * 4;    // 4-col group
#pragma unroll
  for (int i = 0; i < 64; i += 16) {
    const float4 v = *reinterpret_cast<const float4*>(&src[(size_t)(k0 + lr + i) * N + n0 + lc]);
    tile[lr + i][lc] = v.x;
    tile[lr + i][lc + 1] = v.y;
    tile[lr + i][lc + 2] = v.z;
    tile[lr + i][lc + 3] = v.w;
  }
  __syncthreads();
  const int kk = (l & 7) * 8;     // 8-k group
  const int nr = l >> 3;          // 0..31 (n-row within pass)
#pragma unroll
  for (int i = 0; i < 64; i += 32) {
    const int n = nr + i;
    ushort8_t o;
#pragma unroll
    for (int j = 0; j < 8; ++j) o[j] = f2bf(tile[kk + j][n]);
    *reinterpret_cast<ushort8_t*>(&dst[(size_t)(n0 + n) * K + k0 + kk]) = o;
  }
}

// ---------------- kernel 1: transpose w1 + transpose w2 + router -----------
// grid (192,16,8): x<64 -> w1 tile; 64<=x<128 -> w2 tile; x>=128 && z==0 ->
// router block. All three works are independent; memory-bound streaming.
__global__ __launch_bounds__(256) void k_pre(const float* __restrict__ x,
                                             const float* __restrict__ wr,
                                             const float* __restrict__ w1,
                                             unsigned short* __restrict__ WT1,
                                             const float* __restrict__ w2,
                                             unsigned short* __restrict__ WT2,
                                             int* __restrict__ sel, float* __restrict__ wgt) {
  __shared__ __align__(16) char sm[64 * 65 * 4];
  if (blockIdx.x < 64) {  // w1 [E][H][F] -> WT1 [E][F][H]
    transpose_dev(w1 + (size_t)blockIdx.z * H_DIM * F_DIM,
                  WT1 + (size_t)blockIdx.z * F_DIM * H_DIM,
                  H_DIM, F_DIM, blockIdx.x, blockIdx.y, sm);
    return;
  }
  if (blockIdx.x < 128) {  // w2 [E][F][H] -> WT2 [E][H][F]
    if (WT2 == nullptr) return;  // fallback path: skipped
    const int id = blockIdx.y * 64 + (blockIdx.x - 64);  // 1024 tiles per expert
    transpose_dev(w2 + (size_t)blockIdx.z * F_DIM * H_DIM,
                  WT2 + (size_t)blockIdx.z * H_DIM * F_DIM,
                  F_DIM, H_DIM, id & 15, id >> 4, sm);
    return;
  }
  if (blockIdx.z != 0) return;  // router only on z==0 (1024 blocks total)
  const int bid = blockIdx.y * 64 + (blockIdx.x - 128);
  const int t = bid * 4 + (threadIdx.x >> 6);
  const int lane = threadIdx.x & 63;
  const float* xr = x + (size_t)t * H_DIM;
  double acc[E_NUM] = {0, 0, 0, 0, 0, 0, 0, 0};
  for (int h = lane; h < H_DIM; h += 64) {
    const double xv = (double)xr[h];
    const float* w = wr + (size_t)h * E_NUM;
#pragma unroll
    for (int e = 0; e < E_NUM; ++e) acc[e] += xv * (double)w[e];
  }
#pragma unroll
  for (int e = 0; e < E_NUM; ++e) {
#pragma unroll
    for (int off = 32; off > 0; off >>= 1) acc[e] += __shfl_down(acc[e], off, 64);
  }
  if (lane == 0) {
    double m = acc[0];
    int a = 0;
#pragma unroll
    for (int e = 1; e < E_NUM; ++e)
      if (acc[e] > m) { m = acc[e]; a = e; }   // strict > == first-max (jnp.argmax)
    double s = 0.0;
#pragma unroll
    for (int e = 0; e < E_NUM; ++e) s += exp(acc[e] - m);
    sel[t] = a;
    wgt[t] = (float)(1.0 / s);  // softmax prob of the argmax
  }
}

// ---------------- kernel 2: histogram(sel) + exclusive prefix --------------
__global__ void k_prefix(const int* __restrict__ sel, int* __restrict__ offs,
                         int* __restrict__ cursors) {
  __shared__ int h[E_NUM];
  if (threadIdx.x < E_NUM) h[threadIdx.x] = 0;
  __syncthreads();
  for (int i = threadIdx.x; i < T_TOK; i += 256) atomicAdd(&h[sel[i]], 1);
  __syncthreads();
  if (threadIdx.x == 0) {
    int s = 0;
    for (int e = 0; e < E_NUM; ++e) {
      offs[e] = s;
      cursors[e] = s;
      s += h[e];
    }
    offs[E_NUM] = s;  // == T_TOK
  }
}

// ---------------- kernel 3: bucket tokens + gather x rows to bf16 ----------
__global__ void k_scatter(const float* __restrict__ x, const int* __restrict__ sel,
                          const float* __restrict__ wgt, int* __restrict__ cursors,
                          int* __restrict__ s2t, float* __restrict__ wgtS,
                          int* __restrict__ eS, unsigned short* __restrict__ Xs) {
  const int t = blockIdx.x;  // one token per 256-thread block
  __shared__ int sslot;
  if (threadIdx.x == 0) {
    const int e = sel[t];
    const int slot = atomicAdd(&cursors[e], 1);
    sslot = slot;
    s2t[slot] = t;
    wgtS[slot] = wgt[t];
    eS[slot] = e;
  }
  __syncthreads();
  const int slot = sslot;
  const float4 v = reinterpret_cast<const float4*>(x + (size_t)t * H_DIM)[threadIdx.x];
  ushort4 o;
  o.x = f2bf(v.x); o.y = f2bf(v.y); o.z = f2bf(v.z); o.w = f2bf(v.w);
  reinterpret_cast<ushort4*>(Xs + (size_t)slot * H_DIM)[threadIdx.x] = o;
}

// ---------------- kernel 4: FFN1  h = relu(Xs @ w1[e] + b1[e]) -------------
// 128x128 tile, 2-phase pipeline: stage(t+1) issued BEFORE compute(t);
// single __syncthreads()/step (its implicit vmcnt(0) waits only the residual
// of loads that flew under the MFMAs). LDS double-buffered, 64 KB.
__global__ __launch_bounds__(256, 2) void k_ffn1(const unsigned short* __restrict__ Xs,
                                                 const unsigned short* __restrict__ Wt,
                                                 const float* __restrict__ b1,
                                                 unsigned short* __restrict__ Hws,
                                                 const int* __restrict__ offs) {
  const int e = blockIdx.z;
  const int off = offs[e];
  const int cnt = offs[e + 1] - off;
  const int m0 = blockIdx.y * 128;
  if (m0 >= cnt) return;  // uniform early-exit
  const int n0 = blockIdx.x * 128;
  const int msize = cnt - m0;

  __shared__ short lA[2][128 * BK];  // 2 x 16 KB
  __shared__ short lB[2][128 * BK];  // 2 x 16 KB

  const int tid = threadIdx.x;
  const int lane = tid & 63;
  const int wv = tid >> 6;         // 4 waves, 2x2 over 128x128
  const int wm = (wv >> 1) * 64;
  const int wn = (wv & 1) * 64;

  // staging: 8 rows/instr, 8 lanes/row, 16B chunk. XOR-swizzle the GLOBAL
  // chunk by dest row (&7) -> fragment ds_read_b128 measured conflict-free.
  const int sRow = lane >> 3;
  const int cc = lane & 7;
  const int gch = cc ^ sRow;

  const unsigned short* Abase = Xs + (size_t)off * H_DIM;
  const unsigned short* Bbase = Wt + (size_t)e * F_DIM * H_DIM + (size_t)n0 * H_DIM;

  f32x4_t acc[4][4];
#pragma unroll
  for (int i = 0; i < 4; ++i)
#pragma unroll
    for (int j = 0; j < 4; ++j) acc[i][j] = (f32x4_t){0.f, 0.f, 0.f, 0.f};

  const int q = lane >> 4;
  const int r16 = lane & 15;
  const int sw = r16 & 7;  // de-swizzle for fragment reads

  auto stage = [&](int buf, int k0) {
#pragma unroll
    for (int i = 0; i < 4; ++i) {
      const int g = wv * 4 + i;
      const int row = g * 8 + sRow;
      const int ar = (row < msize) ? row : 0;
      gload16(Abase + (size_t)(m0 + ar) * H_DIM + k0 + gch * 8, &lA[buf][g * 8 * BK]);
      gload16(Bbase + (size_t)row * H_DIM + k0 + gch * 8, &lB[buf][g * 8 * BK]);
    }
  };

  stage(0, 0);
  __syncthreads();  // drain prologue loads
  int cur = 0;
  const int NT = H_DIM / BK;  // 16
  for (int t = 0; t < NT; ++t) {
    if (t + 1 < NT) stage(cur ^ 1, (t + 1) * BK);  // issue-early: flies under MFMA
    __builtin_amdgcn_sched_barrier(0);             // pin: stage stays before compute
    __builtin_amdgcn_s_setprio(1);
#pragma unroll
    for (int step = 0; step < 2; ++step) {
      const int slot = (step * 4 + q) ^ sw;
      bhalf8_t af[4], bf[4];
#pragma unroll
      for (int mi = 0; mi < 4; ++mi)
        af[mi] = *reinterpret_cast<const bhalf8_t*>(&lA[cur][(wm + mi * 16 + r16) * BK + slot * 8]);
#pragma unroll
      for (int ni = 0; ni < 4; ++ni)
        bf[ni] = *reinterpret_cast<const bhalf8_t*>(&lB[cur][(wn + ni * 16 + r16) * BK + slot * 8]);
#pragma unroll
      for (int mi = 0; mi < 4; ++mi)
#pragma unroll
        for (int ni = 0; ni < 4; ++ni)
          acc[mi][ni] = __builtin_amdgcn_mfma_f32_16x16x32_bf16(af[mi], bf[ni], acc[mi][ni], 0, 0, 0);
    }
    __builtin_amdgcn_s_setprio(0);
    __syncthreads();  // publishes next tile (residual vmcnt wait) + read-safety
    cur ^= 1;
  }

  // epilogue: bias + relu -> bf16.  C/D map: row = quad*4+reg, col = lane&15
  const int c = lane & 15;
#pragma unroll
  for (int ni = 0; ni < 4; ++ni) {
    const int col = n0 + wn + ni * 16 + c;
    const float bias = b1[e * F_DIM + col];
#pragma unroll
    for (int mi = 0; mi < 4; ++mi) {
      const int rbase = wm + mi * 16 + q * 4;
#pragma unroll
      for (int r = 0; r < 4; ++r) {
        const int row = rbase + r;
        if (row < msize) {
          float v = acc[mi][ni][r] + bias;
          v = fmaxf(v, 0.0f);
          Hws[(size_t)(off + m0 + row) * F_DIM + col] = f2bf(v);
        }
      }
    }
  }
}

// ---------------- kernel 5a: FFN2 split-K main (2-phase pipeline) ----------
// Partial sums (no bias/weight) stored coalesced to P[ks][srow][h] fp32.
__global__ __launch_bounds__(256, 2) void k_ffn2_sk(const unsigned short* __restrict__ Hws,
                                                    const unsigned short* __restrict__ Wt,
                                                    const int* __restrict__ offs,
                                                    float* __restrict__ P) {
  const int e = blockIdx.z >> 1;  // KSPLIT = 2
  const int ks = blockIdx.z & 1;
  const int off = offs[e];
  const int cnt = offs[e + 1] - off;
  const int m0 = blockIdx.y * 128;
  if (m0 >= cnt) return;
  const int n0 = blockIdx.x * 128;
  const int msize = cnt - m0;
  const int kbeg = ks * (F_DIM / KSPLIT);

  __shared__ short lA[2][128 * BK];
  __shared__ short lB[2][128 * BK];

  const int tid = threadIdx.x;
  const int lane = tid & 63;
  const int wv = tid >> 6;
  const int wm = (wv >> 1) * 64;
  const int wn = (wv & 1) * 64;

  const int sRow = lane >> 3;
  const int cc = lane & 7;
  const int gch = cc ^ sRow;

  const unsigned short* Abase = Hws + (size_t)off * F_DIM;
  const unsigned short* Bbase = Wt + (size_t)e * H_DIM * F_DIM + (size_t)n0 * F_DIM;

  f32x4_t acc[4][4];
#pragma unroll
  for (int i = 0; i < 4; ++i)
#pragma unroll
    for (int j = 0; j < 4; ++j) acc[i][j] = (f32x4_t){0.f, 0.f, 0.f, 0.f};

  const int q = lane >> 4;
  const int r16 = lane & 15;
  const int sw = r16 & 7;

  auto stage = [&](int buf, int k0) {
#pragma unroll
    for (int i = 0; i < 4; ++i) {
      const int g = wv * 4 + i;
      const int row = g * 8 + sRow;
      const int ar = (row < msize) ? row : 0;
      gload16(Abase + (size_t)(m0 + ar) * F_DIM + k0 + gch * 8, &lA[buf][g * 8 * BK]);
      gload16(Bbase + (size_t)row * F_DIM + k0 + gch * 8, &lB[buf][g * 8 * BK]);
    }
  };

  stage(0, kbeg);
  __syncthreads();
  int cur = 0;
  const int NT = (F_DIM / KSPLIT) / BK;  // 32
  for (int t = 0; t < NT; ++t) {
    if (t + 1 < NT) stage(cur ^ 1, kbeg + (t + 1) * BK);
    __builtin_amdgcn_sched_barrier(0);
    __builtin_amdgcn_s_setprio(1);
#pragma unroll
    for (int step = 0; step < 2; ++step) {
      const int slot = (step * 4 + q) ^ sw;
      bhalf8_t af[4], bf[4];
#pragma unroll
      for (int mi = 0; mi < 4; ++mi)
        af[mi] = *reinterpret_cast<const bhalf8_t*>(&lA[cur][(wm + mi * 16 + r16) * BK + slot * 8]);
#pragma unroll
      for (int ni = 0; ni < 4; ++ni)
        bf[ni] = *reinterpret_cast<const bhalf8_t*>(&lB[cur][(wn + ni * 16 + r16) * BK + slot * 8]);
#pragma unroll
      for (int mi = 0; mi < 4; ++mi)
#pragma unroll
        for (int ni = 0; ni < 4; ++ni)
          acc[mi][ni] = __builtin_amdgcn_mfma_f32_16x16x32_bf16(af[mi], bf[ni], acc[mi][ni], 0, 0, 0);
    }
    __builtin_amdgcn_s_setprio(0);
    __syncthreads();
    cur ^= 1;
  }

  // epilogue: raw partial sums, coalesced (sorted row order, no scatter here)
  const int c = lane & 15;
  float* Pb = P + (size_t)ks * T_TOK * H_DIM;
#pragma unroll
  for (int mi = 0; mi < 4; ++mi) {
    const int rbase = wm + mi * 16 + q * 4;
#pragma unroll
    for (int r = 0; r < 4; ++r) {
      const int row = rbase + r;
      if (row >= msize) continue;
      float* prow = Pb + (size_t)(off + m0 + row) * H_DIM;
#pragma unroll
      for (int ni = 0; ni < 4; ++ni) prow[n0 + wn + ni * 16 + c] = acc[mi][ni][r];
    }
  }
}

// ---------------- kernel 5b: split-K reduce + bias + weight + scatter ------
__global__ __launch_bounds__(256) void k_reduce(const float* __restrict__ P,
                                                const float* __restrict__ b2,
                                                const int* __restrict__ s2t,
                                                const int* __restrict__ eS,
                                                const float* __restrict__ wgtS,
                                                float* __restrict__ out) {
  const int srow = blockIdx.x;
  const int tok = s2t[srow];
  const int e = eS[srow];
  const float w = wgtS[srow];
  const int i = threadIdx.x;  // 256 threads x float4 = 1024 = H
  const size_t rowoff = (size_t)srow * H_DIM / 4 + i;
  const float4 p0 = reinterpret_cast<const float4*>(P)[rowoff];
  const float4 p1 = reinterpret_cast<const float4*>(P + (size_t)T_TOK * H_DIM)[rowoff];
  const float4 b = reinterpret_cast<const float4*>(b2 + (size_t)e * H_DIM)[i];
  float4 o;
  o.x = w * (p0.x + p1.x + b.x);
  o.y = w * (p0.y + p1.y + b.y);
  o.z = w * (p0.z + p1.z + b.z);
  o.w = w * (p0.w + p1.w + b.w);
  reinterpret_cast<float4*>(out + (size_t)tok * H_DIM)[i] = o;
}

// ---------------- standalone transpose (fallback path only) ----------------
__global__ __launch_bounds__(256) void k_transpose(const float* __restrict__ in,
                                                   unsigned short* __restrict__ out,
                                                   int K, int N) {
  __shared__ __align__(16) char sm[64 * 65 * 4];
  transpose_dev(in + (size_t)blockIdx.z * K * N, out + (size_t)blockIdx.z * N * K,
                K, N, blockIdx.x, blockIdx.y, sm);
}

// ---------------- kernel 5c: FFN2 direct (fallback if ws too small) --------
__global__ __launch_bounds__(256, 4) void k_ffn2_direct(const unsigned short* __restrict__ Hws,
                                                        const unsigned short* __restrict__ Wt,
                                                        const float* __restrict__ b2,
                                                        const int* __restrict__ offs,
                                                        const int* __restrict__ s2t,
                                                        const float* __restrict__ wgtS,
                                                        float* __restrict__ out) {
  const int e = blockIdx.z;
  const int off = offs[e];
  const int cnt = offs[e + 1] - off;
  const int m0 = blockIdx.y * 128;
  if (m0 >= cnt) return;
  const int n0 = blockIdx.x * 128;
  const int msize = cnt - m0;

  __shared__ short lA[128 * BK];
  __shared__ short lB[128 * BK];

  const int tid = threadIdx.x;
  const int lane = tid & 63;
  const int wv = tid >> 6;
  const int wm = (wv >> 1) * 64;
  const int wn = (wv & 1) * 64;

  const int sRow = lane >> 3;
  const int cc = lane & 7;
  const int gch = cc ^ sRow;

  const unsigned short* Abase = Hws + (size_t)off * F_DIM;
  const unsigned short* Bbase = Wt + (size_t)e * H_DIM * F_DIM + (size_t)n0 * F_DIM;

  f32x4_t acc[4][4];
#pragma unroll
  for (int i = 0; i < 4; ++i)
#pragma unroll
    for (int j = 0; j < 4; ++j) acc[i][j] = (f32x4_t){0.f, 0.f, 0.f, 0.f};

  const int q = lane >> 4;
  const int r16 = lane & 15;
  const int sw = r16 & 7;

  for (int k0 = 0; k0 < F_DIM; k0 += BK) {
    __syncthreads();
#pragma unroll
    for (int i = 0; i < 4; ++i) {
      const int g = wv * 4 + i;
      const int row = g * 8 + sRow;
      const int ar = (row < msize) ? row : 0;
      gload16(Abase + (size_t)(m0 + ar) * F_DIM + k0 + gch * 8, &lA[g * 8 * BK]);
      gload16(Bbase + (size_t)row * F_DIM + k0 + gch * 8, &lB[g * 8 * BK]);
    }
    __syncthreads();

#pragma unroll
    for (int step = 0; step < 2; ++step) {
      const int slot = (step * 4 + q) ^ sw;
      bhalf8_t af[4], bf[4];
#pragma unroll
      for (int mi = 0; mi < 4; ++mi)
        af[mi] = *reinterpret_cast<const bhalf8_t*>(&lA[(wm + mi * 16 + r16) * BK + slot * 8]);
#pragma unroll
      for (int ni = 0; ni < 4; ++ni)
        bf[ni] = *reinterpret_cast<const bhalf8_t*>(&lB[(wn + ni * 16 + r16) * BK + slot * 8]);
#pragma unroll
      for (int mi = 0; mi < 4; ++mi)
#pragma unroll
        for (int ni = 0; ni < 4; ++ni)
          acc[mi][ni] = __builtin_amdgcn_mfma_f32_16x16x32_bf16(af[mi], bf[ni], acc[mi][ni], 0, 0, 0);
    }
  }

  const int c = lane & 15;
#pragma unroll
  for (int mi = 0; mi < 4; ++mi) {
    const int rbase = wm + mi * 16 + q * 4;
#pragma unroll
    for (int r = 0; r < 4; ++r) {
      const int row = rbase + r;
      if (row >= msize) continue;
      const int srow = off + m0 + row;
      const int tok = s2t[srow];
      const float w = wgtS[srow];
      float* orow = out + (size_t)tok * H_DIM;
#pragma unroll
      for (int ni = 0; ni < 4; ++ni) {
        const int col = n0 + wn + ni * 16 + c;
        orow[col] = w * (acc[mi][ni][r] + b2[e * H_DIM + col]);
      }
    }
  }
}

extern "C" void kernel_launch(void* const* d_in, const int* in_sizes, int n_in,
                              void* d_out, int out_size, void* d_ws, size_t ws_size,
                              hipStream_t stream) {
  const float* x  = (const float*)d_in[0];   // [2,2048,1024]
  const float* wr = (const float*)d_in[1];   // [1024,8]
  const float* w1 = (const float*)d_in[2];   // [8,1024,4096]
  const float* b1 = (const float*)d_in[3];   // [8,4096]
  const float* w2 = (const float*)d_in[4];   // [8,4096,1024]
  const float* b2 = (const float*)d_in[5];   // [8,1024]
  float* out = (float*)d_out;                // [2,2048,1024]

  char* ws = (char*)d_ws;
  // Fast path layout: WT1 64MB | WT2 64MB | XS 8MB | HWS 32MB | ctrl 96KB.
  // P (split-K partials, KSPLIT*16.8MB) aliases WT1: WT1's last reader
  // (k_ffn1) completes before k_ffn2_sk writes P (stream order).
  const size_t NEED_FAST = 67108864ull * 2 + 8388608 + 33554432 + 98304;  // 176259072
  if (ws_size >= NEED_FAST) {
    unsigned short* WT1 = (unsigned short*)(ws);
    unsigned short* WT2 = (unsigned short*)(ws + 67108864);
    unsigned short* XS  = (unsigned short*)(ws + 134217728);
    unsigned short* HWS = (unsigned short*)(ws + 142606336);
    char* ctrl = ws + 176160768;
    int*   sel     = (int*)(ctrl);
    int*   s2t     = (int*)(ctrl + 16384);
    float* wgt     = (float*)(ctrl + 32768);
    float* wgtS    = (float*)(ctrl + 49152);
    int*   eS      = (int*)(ctrl + 65536);
    int*   offs    = (int*)(ctrl + 81920);
    int*   cursors = (int*)(ctrl + 81984);
    float* P = (float*)ws;  // alias WT1

    k_pre<<<dim3(192, 16, 8), 256, 0, stream>>>(x, wr, w1, WT1, w2, WT2, sel, wgt);
    k_prefix<<<1, 256, 0, stream>>>(sel, offs, cursors);
    k_scatter<<<T_TOK, 256, 0, stream>>>(x, sel, wgt, cursors, s2t, wgtS, eS, XS);
    k_ffn1<<<dim3(F_DIM / 128, T_TOK / 128, E_NUM), 256, 0, stream>>>(XS, WT1, b1, HWS, offs);
    k_ffn2_sk<<<dim3(H_DIM / 128, T_TOK / 128, E_NUM * KSPLIT), 256, 0, stream>>>(HWS, WT2, offs, P);
    k_reduce<<<T_TOK, 256, 0, stream>>>(P, b2, s2t, eS, wgtS, out);
  } else {
    // Fallback: single WT buffer, sequential transposes, direct ffn2.
    unsigned short* WT  = (unsigned short*)(ws);
    unsigned short* XS  = (unsigned short*)(ws + 67108864);
    unsigned short* HWS = (unsigned short*)(ws + 75497472);
    char* ctrl = ws + 109051904;
    int*   sel     = (int*)(ctrl);
    int*   s2t     = (int*)(ctrl + 16384);
    float* wgt     = (float*)(ctrl + 32768);
    float* wgtS    = (float*)(ctrl + 49152);
    int*   eS      = (int*)(ctrl + 65536);
    int*   offs    = (int*)(ctrl + 81920);
    int*   cursors = (int*)(ctrl + 81984);

    k_pre<<<dim3(192, 16, 8), 256, 0, stream>>>(x, wr, w1, WT, w2, (unsigned short*)0, sel, wgt);
    k_prefix<<<1, 256, 0, stream>>>(sel, offs, cursors);
    k_scatter<<<T_TOK, 256, 0, stream>>>(x, sel, wgt, cursors, s2t, wgtS, eS, XS);
    k_ffn1<<<dim3(F_DIM / 128, T_TOK / 128, E_NUM), 256, 0, stream>>>(XS, WT, b1, HWS, offs);
    k_transpose<<<dim3(H_DIM / 64, F_DIM / 64, E_NUM), 256, 0, stream>>>(w2, WT, F_DIM, H_DIM);
    k_ffn2_direct<<<dim3(H_DIM / 128, T_TOK / 128, E_NUM), 256, 0, stream>>>(HWS, WT, b2, offs, s2t, wgtS, out);
  }
}

// Round 4
// 512.970 us; speedup vs baseline: 1.0460x; 1.0460x over previous
//
#include <hip/hip_runtime.h>
#include <math.h>

// Problem constants (B=2,S=2048 -> T=4096 tokens)
#define T_TOK 4096
#define H_DIM 1024
#define F_DIM 4096
#define E_NUM 8
#define BK 64
#define KSPLIT 4  // ffn2 split-K (fast path)

typedef __attribute__((ext_vector_type(8))) short bhalf8_t;
typedef __attribute__((ext_vector_type(8))) unsigned short ushort8_t;
typedef __attribute__((ext_vector_type(4))) float f32x4_t;

// fp32 -> bf16 round-to-nearest-even
__device__ __forceinline__ unsigned short f2bf(float f) {
  unsigned int u = __float_as_uint(f);
  return (unsigned short)((u + 0x7fffu + ((u >> 16) & 1u)) >> 16);
}

// async global->LDS, 16B per lane. LDS dest = wave-uniform base + lane*16.
__device__ __forceinline__ void gload16(const void* g, void* l) {
  __builtin_amdgcn_global_load_lds(
      (const __attribute__((address_space(1))) unsigned int*)g,
      (__attribute__((address_space(3))) unsigned int*)l, 16, 0, 0);
}

// ---- wide transpose tile: fp32 [K][N] 64x256 tile -> bf16 [N][K] ----------
// Reads 1KB contiguous per row (16 dwordx4 in flight per thread), converts
// to bf16 before LDS (33KB, 4 blocks/CU), writes 128B segments per dst row.
// LDS stride 260 bf16 = 130 words (=2 mod 32): b64 writes bank-uniform.
#define TP_LDSTRIDE 260
__device__ __forceinline__ void transpose_wide(const float* __restrict__ src,
                                               unsigned short* __restrict__ dst,
                                               int K, int N, int k0, int n0,
                                               unsigned short* lds) {
  const int t = threadIdx.x;
  float4 v[16];
#pragma unroll
  for (int i = 0; i < 16; ++i) {
    const int c = i * 256 + t;
    const int row = c >> 6;          // 0..63
    const int col = (c & 63) * 4;    // 0..252
    v[i] = *reinterpret_cast<const float4*>(&src[(size_t)(k0 + row) * N + n0 + col]);
  }
#pragma unroll
  for (int i = 0; i < 16; ++i) {
    const int c = i * 256 + t;
    const int row = c >> 6;
    const int col = (c & 63) * 4;
    ushort4 o;
    o.x = f2bf(v[i].x); o.y = f2bf(v[i].y); o.z = f2bf(v[i].z); o.w = f2bf(v[i].w);
    *reinterpret_cast<ushort4*>(&lds[row * TP_LDSTRIDE + col]) = o;
  }
  __syncthreads();
#pragma unroll
  for (int i = 0; i < 8; ++i) {
    const int oc = i * 256 + t;
    const int n = oc >> 3;           // 0..255
    const int c = oc & 7;            // k chunk: 8 bf16
    ushort8_t o;
#pragma unroll
    for (int j = 0; j < 8; ++j) o[j] = lds[(c * 8 + j) * TP_LDSTRIDE + n];
    *reinterpret_cast<ushort8_t*>(&dst[(size_t)(n0 + n) * K + k0 + c * 8]) = o;
  }
}

// ---------------- kernel 1: transpose w1 + transpose w2 + router -----------
// Flat grid of 5120 blocks: id%5==4 -> router token-group (1024 of them),
// else transpose tile (4096: 2048 w1 + 2048 w2), interleaved for overlap.
__global__ __launch_bounds__(256) void k_pre(const float* __restrict__ x,
                                             const float* __restrict__ wr,
                                             const float* __restrict__ w1,
                                             unsigned short* __restrict__ WT1,
                                             const float* __restrict__ w2,
                                             unsigned short* __restrict__ WT2,
                                             int* __restrict__ sel, float* __restrict__ wgt) {
  __shared__ __align__(16) unsigned short lds[64 * TP_LDSTRIDE];  // 33280 B
  const unsigned int id = blockIdx.x;
  const unsigned int r = id % 5u;
  const unsigned int q = id / 5u;
  if (r < 4u) {
    const int tid4 = (int)(q * 4u + r);  // 0..4095
    if (tid4 < 2048) {  // w1 [E][H][F] -> WT1 [E][F][H]  (K=H, N=F)
      const int e = tid4 >> 8;
      const int tt = tid4 & 255;
      transpose_wide(w1 + (size_t)e * H_DIM * F_DIM, WT1 + (size_t)e * F_DIM * H_DIM,
                     H_DIM, F_DIM, (tt >> 4) * 64, (tt & 15) * 256, lds);
    } else {            // w2 [E][F][H] -> WT2 [E][H][F]  (K=F, N=H)
      if (WT2 == nullptr) return;  // fallback path skips w2 here
      const int t2 = tid4 - 2048;
      const int e = t2 >> 8;
      const int tt = t2 & 255;
      transpose_wide(w2 + (size_t)e * F_DIM * H_DIM, WT2 + (size_t)e * H_DIM * F_DIM,
                     F_DIM, H_DIM, (tt >> 2) * 64, (tt & 3) * 256, lds);
    }
    return;
  }
  // ---- router: 1024 blocks x 4 tokens ----
  const int t = (int)q * 4 + (threadIdx.x >> 6);
  const int lane = threadIdx.x & 63;
  const float* xr = x + (size_t)t * H_DIM;
  double acc[E_NUM] = {0, 0, 0, 0, 0, 0, 0, 0};
  for (int h = lane; h < H_DIM; h += 64) {
    const double xv = (double)xr[h];
    const float* w = wr + (size_t)h * E_NUM;
#pragma unroll
    for (int e = 0; e < E_NUM; ++e) acc[e] += xv * (double)w[e];
  }
#pragma unroll
  for (int e = 0; e < E_NUM; ++e) {
#pragma unroll
    for (int off = 32; off > 0; off >>= 1) acc[e] += __shfl_down(acc[e], off, 64);
  }
  if (lane == 0) {
    double m = acc[0];
    int a = 0;
#pragma unroll
    for (int e = 1; e < E_NUM; ++e)
      if (acc[e] > m) { m = acc[e]; a = e; }   // strict > == first-max (jnp.argmax)
    double s = 0.0;
#pragma unroll
    for (int e = 0; e < E_NUM; ++e) s += exp(acc[e] - m);
    sel[t] = a;
    wgt[t] = (float)(1.0 / s);  // softmax prob of the argmax
  }
}

// ---------------- kernel 2: histogram(sel) + exclusive prefix --------------
__global__ void k_prefix(const int* __restrict__ sel, int* __restrict__ offs,
                         int* __restrict__ cursors) {
  __shared__ int h[E_NUM];
  if (threadIdx.x < E_NUM) h[threadIdx.x] = 0;
  __syncthreads();
  for (int i = threadIdx.x; i < T_TOK; i += 256) atomicAdd(&h[sel[i]], 1);
  __syncthreads();
  if (threadIdx.x == 0) {
    int s = 0;
    for (int e = 0; e < E_NUM; ++e) {
      offs[e] = s;
      cursors[e] = s;
      s += h[e];
    }
    offs[E_NUM] = s;  // == T_TOK
  }
}

// ---------------- kernel 3: bucket tokens + gather x rows to bf16 ----------
__global__ void k_scatter(const float* __restrict__ x, const int* __restrict__ sel,
                          const float* __restrict__ wgt, int* __restrict__ cursors,
                          int* __restrict__ s2t, float* __restrict__ wgtS,
                          int* __restrict__ eS, unsigned short* __restrict__ Xs) {
  const int t = blockIdx.x;  // one token per 256-thread block
  __shared__ int sslot;
  if (threadIdx.x == 0) {
    const int e = sel[t];
    const int slot = atomicAdd(&cursors[e], 1);
    sslot = slot;
    s2t[slot] = t;
    wgtS[slot] = wgt[t];
    eS[slot] = e;
  }
  __syncthreads();
  const int slot = sslot;
  const float4 v = reinterpret_cast<const float4*>(x + (size_t)t * H_DIM)[threadIdx.x];
  ushort4 o;
  o.x = f2bf(v.x); o.y = f2bf(v.y); o.z = f2bf(v.z); o.w = f2bf(v.w);
  reinterpret_cast<ushort4*>(Xs + (size_t)slot * H_DIM)[threadIdx.x] = o;
}

// ---------------- kernel 4: FFN1  h = relu(Xs @ w1[e] + b1[e]) -------------
// 128x128 tile, single-buffer 32KB LDS, 4 blocks/CU (proven structure).
__global__ __launch_bounds__(256, 4) void k_ffn1(const unsigned short* __restrict__ Xs,
                                                 const unsigned short* __restrict__ Wt,
                                                 const float* __restrict__ b1,
                                                 unsigned short* __restrict__ Hws,
                                                 const int* __restrict__ offs) {
  const int e = blockIdx.z;
  const int off = offs[e];
  const int cnt = offs[e + 1] - off;
  const int m0 = blockIdx.y * 128;
  if (m0 >= cnt) return;  // uniform early-exit
  const int n0 = blockIdx.x * 128;
  const int msize = cnt - m0;

  __shared__ short lA[128 * BK];  // 16 KB
  __shared__ short lB[128 * BK];  // 16 KB

  const int tid = threadIdx.x;
  const int lane = tid & 63;
  const int wv = tid >> 6;         // 4 waves, 2x2 over 128x128
  const int wm = (wv >> 1) * 64;
  const int wn = (wv & 1) * 64;

  // staging: 8 rows/instr, 8 lanes/row, 16B chunk. XOR-swizzle the GLOBAL
  // chunk by dest row (&7) -> fragment ds_read_b128 measured conflict-free.
  const int sRow = lane >> 3;
  const int cc = lane & 7;
  const int gch = cc ^ sRow;

  const unsigned short* Abase = Xs + (size_t)off * H_DIM;
  const unsigned short* Bbase = Wt + (size_t)e * F_DIM * H_DIM + (size_t)n0 * H_DIM;

  f32x4_t acc[4][4];
#pragma unroll
  for (int i = 0; i < 4; ++i)
#pragma unroll
    for (int j = 0; j < 4; ++j) acc[i][j] = (f32x4_t){0.f, 0.f, 0.f, 0.f};

  const int q = lane >> 4;
  const int r16 = lane & 15;
  const int sw = r16 & 7;  // de-swizzle for fragment reads

  for (int k0 = 0; k0 < H_DIM; k0 += BK) {
    __syncthreads();
#pragma unroll
    for (int i = 0; i < 4; ++i) {
      const int g = wv * 4 + i;
      const int row = g * 8 + sRow;
      const int ar = (row < msize) ? row : 0;
      gload16(Abase + (size_t)(m0 + ar) * H_DIM + k0 + gch * 8, &lA[g * 8 * BK]);
      gload16(Bbase + (size_t)row * H_DIM + k0 + gch * 8, &lB[g * 8 * BK]);
    }
    __syncthreads();  // drains vmcnt for global_load_lds

#pragma unroll
    for (int step = 0; step < 2; ++step) {
      const int slot = (step * 4 + q) ^ sw;
      bhalf8_t af[4], bf[4];
#pragma unroll
      for (int mi = 0; mi < 4; ++mi)
        af[mi] = *reinterpret_cast<const bhalf8_t*>(&lA[(wm + mi * 16 + r16) * BK + slot * 8]);
#pragma unroll
      for (int ni = 0; ni < 4; ++ni)
        bf[ni] = *reinterpret_cast<const bhalf8_t*>(&lB[(wn + ni * 16 + r16) * BK + slot * 8]);
#pragma unroll
      for (int mi = 0; mi < 4; ++mi)
#pragma unroll
        for (int ni = 0; ni < 4; ++ni)
          acc[mi][ni] = __builtin_amdgcn_mfma_f32_16x16x32_bf16(af[mi], bf[ni], acc[mi][ni], 0, 0, 0);
    }
  }

  // epilogue: bias + relu -> bf16.  C/D map: row = quad*4+reg, col = lane&15
  const int c = lane & 15;
#pragma unroll
  for (int ni = 0; ni < 4; ++ni) {
    const int col = n0 + wn + ni * 16 + c;
    const float bias = b1[e * F_DIM + col];
#pragma unroll
    for (int mi = 0; mi < 4; ++mi) {
      const int rbase = wm + mi * 16 + q * 4;
#pragma unroll
      for (int r = 0; r < 4; ++r) {
        const int row = rbase + r;
        if (row < msize) {
          float v = acc[mi][ni][r] + bias;
          v = fmaxf(v, 0.0f);
          Hws[(size_t)(off + m0 + row) * F_DIM + col] = f2bf(v);
        }
      }
    }
  }
}

// ---------------- kernel 5a: FFN2 split-K main -----------------------------
// Partial sums (no bias/weight) stored coalesced to P[ks][srow][h] fp32.
__global__ __launch_bounds__(256, 4) void k_ffn2_sk(const unsigned short* __restrict__ Hws,
                                                    const unsigned short* __restrict__ Wt,
                                                    const int* __restrict__ offs,
                                                    float* __restrict__ P) {
  const int e = blockIdx.z >> 2;  // KSPLIT = 4
  const int ks = blockIdx.z & 3;
  const int off = offs[e];
  const int cnt = offs[e + 1] - off;
  const int m0 = blockIdx.y * 128;
  if (m0 >= cnt) return;
  const int n0 = blockIdx.x * 128;
  const int msize = cnt - m0;
  const int kbeg = ks * (F_DIM / KSPLIT);
  const int kend = kbeg + (F_DIM / KSPLIT);

  __shared__ short lA[128 * BK];
  __shared__ short lB[128 * BK];

  const int tid = threadIdx.x;
  const int lane = tid & 63;
  const int wv = tid >> 6;
  const int wm = (wv >> 1) * 64;
  const int wn = (wv & 1) * 64;

  const int sRow = lane >> 3;
  const int cc = lane & 7;
  const int gch = cc ^ sRow;

  const unsigned short* Abase = Hws + (size_t)off * F_DIM;
  const unsigned short* Bbase = Wt + (size_t)e * H_DIM * F_DIM + (size_t)n0 * F_DIM;

  f32x4_t acc[4][4];
#pragma unroll
  for (int i = 0; i < 4; ++i)
#pragma unroll
    for (int j = 0; j < 4; ++j) acc[i][j] = (f32x4_t){0.f, 0.f, 0.f, 0.f};

  const int q = lane >> 4;
  const int r16 = lane & 15;
  const int sw = r16 & 7;

  for (int k0 = kbeg; k0 < kend; k0 += BK) {
    __syncthreads();
#pragma unroll
    for (int i = 0; i < 4; ++i) {
      const int g = wv * 4 + i;
      const int row = g * 8 + sRow;
      const int ar = (row < msize) ? row : 0;
      gload16(Abase + (size_t)(m0 + ar) * F_DIM + k0 + gch * 8, &lA[g * 8 * BK]);
      gload16(Bbase + (size_t)row * F_DIM + k0 + gch * 8, &lB[g * 8 * BK]);
    }
    __syncthreads();

#pragma unroll
    for (int step = 0; step < 2; ++step) {
      const int slot = (step * 4 + q) ^ sw;
      bhalf8_t af[4], bf[4];
#pragma unroll
      for (int mi = 0; mi < 4; ++mi)
        af[mi] = *reinterpret_cast<const bhalf8_t*>(&lA[(wm + mi * 16 + r16) * BK + slot * 8]);
#pragma unroll
      for (int ni = 0; ni < 4; ++ni)
        bf[ni] = *reinterpret_cast<const bhalf8_t*>(&lB[(wn + ni * 16 + r16) * BK + slot * 8]);
#pragma unroll
      for (int mi = 0; mi < 4; ++mi)
#pragma unroll
        for (int ni = 0; ni < 4; ++ni)
          acc[mi][ni] = __builtin_amdgcn_mfma_f32_16x16x32_bf16(af[mi], bf[ni], acc[mi][ni], 0, 0, 0);
    }
  }

  // epilogue: raw partial sums, coalesced (sorted row order, no scatter here)
  const int c = lane & 15;
  float* Pb = P + (size_t)ks * T_TOK * H_DIM;
#pragma unroll
  for (int mi = 0; mi < 4; ++mi) {
    const int rbase = wm + mi * 16 + q * 4;
#pragma unroll
    for (int r = 0; r < 4; ++r) {
      const int row = rbase + r;
      if (row >= msize) continue;
      float* prow = Pb + (size_t)(off + m0 + row) * H_DIM;
#pragma unroll
      for (int ni = 0; ni < 4; ++ni) prow[n0 + wn + ni * 16 + c] = acc[mi][ni][r];
    }
  }
}

// ---------------- kernel 5b: split-K reduce + bias + weight + scatter ------
__global__ __launch_bounds__(256) void k_reduce(const float* __restrict__ P,
                                                const float* __restrict__ b2,
                                                const int* __restrict__ s2t,
                                                const int* __restrict__ eS,
                                                const float* __restrict__ wgtS,
                                                float* __restrict__ out) {
  const int srow = blockIdx.x;
  const int tok = s2t[srow];
  const int e = eS[srow];
  const float w = wgtS[srow];
  const int i = threadIdx.x;  // 256 threads x float4 = 1024 = H
  const size_t rowoff = (size_t)srow * H_DIM / 4 + i;
  const float4 p0 = reinterpret_cast<const float4*>(P)[rowoff];
  const float4 p1 = reinterpret_cast<const float4*>(P + (size_t)T_TOK * H_DIM)[rowoff];
  const float4 p2 = reinterpret_cast<const float4*>(P + (size_t)2 * T_TOK * H_DIM)[rowoff];
  const float4 p3 = reinterpret_cast<const float4*>(P + (size_t)3 * T_TOK * H_DIM)[rowoff];
  const float4 b = reinterpret_cast<const float4*>(b2 + (size_t)e * H_DIM)[i];
  float4 o;
  o.x = w * (p0.x + p1.x + p2.x + p3.x + b.x);
  o.y = w * (p0.y + p1.y + p2.y + p3.y + b.y);
  o.z = w * (p0.z + p1.z + p2.z + p3.z + b.z);
  o.w = w * (p0.w + p1.w + p2.w + p3.w + b.w);
  reinterpret_cast<float4*>(out + (size_t)tok * H_DIM)[i] = o;
}

// ---------------- standalone transpose (fallback path only) ----------------
__device__ __forceinline__ void transpose_dev(const float* __restrict__ src,
                                              unsigned short* __restrict__ dst,
                                              int K, int N, int bx, int by, void* sm_) {
  float(*tile)[65] = (float(*)[65])sm_;  // 64x65 fp32, +1 pad
  const int n0 = bx * 64;
  const int k0 = by * 64;
  const int l = threadIdx.x;
  const int lr = l >> 4;          // 0..15 (k-row within pass)
  const int lc = (l & 15) * 4;    // 4-col group
#pragma unroll
  for (int i = 0; i < 64; i += 16) {
    const float4 v = *reinterpret_cast<const float4*>(&src[(size_t)(k0 + lr + i) * N + n0 + lc]);
    tile[lr + i][lc] = v.x;
    tile[lr + i][lc + 1] = v.y;
    tile[lr + i][lc + 2] = v.z;
    tile[lr + i][lc + 3] = v.w;
  }
  __syncthreads();
  const int kk = (l & 7) * 8;     // 8-k group
  const int nr = l >> 3;          // 0..31 (n-row within pass)
#pragma unroll
  for (int i = 0; i < 64; i += 32) {
    const int n = nr + i;
    ushort8_t o;
#pragma unroll
    for (int j = 0; j < 8; ++j) o[j] = f2bf(tile[kk + j][n]);
    *reinterpret_cast<ushort8_t*>(&dst[(size_t)(n0 + n) * K + k0 + kk]) = o;
  }
}

__global__ __launch_bounds__(256) void k_transpose(const float* __restrict__ in,
                                                   unsigned short* __restrict__ out,
                                                   int K, int N) {
  __shared__ __align__(16) char sm[64 * 65 * 4];
  transpose_dev(in + (size_t)blockIdx.z * K * N, out + (size_t)blockIdx.z * N * K,
                K, N, blockIdx.x, blockIdx.y, sm);
}

// ---------------- kernel 5c: FFN2 direct (fallback if ws too small) --------
__global__ __launch_bounds__(256, 4) void k_ffn2_direct(const unsigned short* __restrict__ Hws,
                                                        const unsigned short* __restrict__ Wt,
                                                        const float* __restrict__ b2,
                                                        const int* __restrict__ offs,
                                                        const int* __restrict__ s2t,
                                                        const float* __restrict__ wgtS,
                                                        float* __restrict__ out) {
  const int e = blockIdx.z;
  const int off = offs[e];
  const int cnt = offs[e + 1] - off;
  const int m0 = blockIdx.y * 128;
  if (m0 >= cnt) return;
  const int n0 = blockIdx.x * 128;
  const int msize = cnt - m0;

  __shared__ short lA[128 * BK];
  __shared__ short lB[128 * BK];

  const int tid = threadIdx.x;
  const int lane = tid & 63;
  const int wv = tid >> 6;
  const int wm = (wv >> 1) * 64;
  const int wn = (wv & 1) * 64;

  const int sRow = lane >> 3;
  const int cc = lane & 7;
  const int gch = cc ^ sRow;

  const unsigned short* Abase = Hws + (size_t)off * F_DIM;
  const unsigned short* Bbase = Wt + (size_t)e * H_DIM * F_DIM + (size_t)n0 * F_DIM;

  f32x4_t acc[4][4];
#pragma unroll
  for (int i = 0; i < 4; ++i)
#pragma unroll
    for (int j = 0; j < 4; ++j) acc[i][j] = (f32x4_t){0.f, 0.f, 0.f, 0.f};

  const int q = lane >> 4;
  const int r16 = lane & 15;
  const int sw = r16 & 7;

  for (int k0 = 0; k0 < F_DIM; k0 += BK) {
    __syncthreads();
#pragma unroll
    for (int i = 0; i < 4; ++i) {
      const int g = wv * 4 + i;
      const int row = g * 8 + sRow;
      const int ar = (row < msize) ? row : 0;
      gload16(Abase + (size_t)(m0 + ar) * F_DIM + k0 + gch * 8, &lA[g * 8 * BK]);
      gload16(Bbase + (size_t)row * F_DIM + k0 + gch * 8, &lB[g * 8 * BK]);
    }
    __syncthreads();

#pragma unroll
    for (int step = 0; step < 2; ++step) {
      const int slot = (step * 4 + q) ^ sw;
      bhalf8_t af[4], bf[4];
#pragma unroll
      for (int mi = 0; mi < 4; ++mi)
        af[mi] = *reinterpret_cast<const bhalf8_t*>(&lA[(wm + mi * 16 + r16) * BK + slot * 8]);
#pragma unroll
      for (int ni = 0; ni < 4; ++ni)
        bf[ni] = *reinterpret_cast<const bhalf8_t*>(&lB[(wn + ni * 16 + r16) * BK + slot * 8]);
#pragma unroll
      for (int mi = 0; mi < 4; ++mi)
#pragma unroll
        for (int ni = 0; ni < 4; ++ni)
          acc[mi][ni] = __builtin_amdgcn_mfma_f32_16x16x32_bf16(af[mi], bf[ni], acc[mi][ni], 0, 0, 0);
    }
  }

  const int c = lane & 15;
#pragma unroll
  for (int mi = 0; mi < 4; ++mi) {
    const int rbase = wm + mi * 16 + q * 4;
#pragma unroll
    for (int r = 0; r < 4; ++r) {
      const int row = rbase + r;
      if (row >= msize) continue;
      const int srow = off + m0 + row;
      const int tok = s2t[srow];
      const float w = wgtS[srow];
      float* orow = out + (size_t)tok * H_DIM;
#pragma unroll
      for (int ni = 0; ni < 4; ++ni) {
        const int col = n0 + wn + ni * 16 + c;
        orow[col] = w * (acc[mi][ni][r] + b2[e * H_DIM + col]);
      }
    }
  }
}

extern "C" void kernel_launch(void* const* d_in, const int* in_sizes, int n_in,
                              void* d_out, int out_size, void* d_ws, size_t ws_size,
                              hipStream_t stream) {
  const float* x  = (const float*)d_in[0];   // [2,2048,1024]
  const float* wr = (const float*)d_in[1];   // [1024,8]
  const float* w1 = (const float*)d_in[2];   // [8,1024,4096]
  const float* b1 = (const float*)d_in[3];   // [8,4096]
  const float* w2 = (const float*)d_in[4];   // [8,4096,1024]
  const float* b2 = (const float*)d_in[5];   // [8,1024]
  float* out = (float*)d_out;                // [2,2048,1024]

  char* ws = (char*)d_ws;
  // Fast path layout: WT1 64MB | WT2 64MB | XS 8MB | HWS 32MB | ctrl 96KB.
  // P (split-K partials, 64MB) aliases WT1: WT1's last reader (k_ffn1)
  // completes before k_ffn2_sk writes P (stream order).
  const size_t NEED_FAST = 67108864ull * 2 + 8388608 + 33554432 + 98304;  // 176259072
  if (ws_size >= NEED_FAST) {
    unsigned short* WT1 = (unsigned short*)(ws);
    unsigned short* WT2 = (unsigned short*)(ws + 67108864);
    unsigned short* XS  = (unsigned short*)(ws + 134217728);
    unsigned short* HWS = (unsigned short*)(ws + 142606336);
    char* ctrl = ws + 176160768;
    int*   sel     = (int*)(ctrl);
    int*   s2t     = (int*)(ctrl + 16384);
    float* wgt     = (float*)(ctrl + 32768);
    float* wgtS    = (float*)(ctrl + 49152);
    int*   eS      = (int*)(ctrl + 65536);
    int*   offs    = (int*)(ctrl + 81920);
    int*   cursors = (int*)(ctrl + 81984);
    float* P = (float*)ws;  // alias WT1 (exactly 64MB for KSPLIT=4)

    k_pre<<<5120, 256, 0, stream>>>(x, wr, w1, WT1, w2, WT2, sel, wgt);
    k_prefix<<<1, 256, 0, stream>>>(sel, offs, cursors);
    k_scatter<<<T_TOK, 256, 0, stream>>>(x, sel, wgt, cursors, s2t, wgtS, eS, XS);
    k_ffn1<<<dim3(F_DIM / 128, T_TOK / 128, E_NUM), 256, 0, stream>>>(XS, WT1, b1, HWS, offs);
    k_ffn2_sk<<<dim3(H_DIM / 128, T_TOK / 128, E_NUM * KSPLIT), 256, 0, stream>>>(HWS, WT2, offs, P);
    k_reduce<<<T_TOK, 256, 0, stream>>>(P, b2, s2t, eS, wgtS, out);
  } else {
    // Fallback: single WT buffer, sequential transposes, direct ffn2.
    unsigned short* WT  = (unsigned short*)(ws);
    unsigned short* XS  = (unsigned short*)(ws + 67108864);
    unsigned short* HWS = (unsigned short*)(ws + 75497472);
    char* ctrl = ws + 109051904;
    int*   sel     = (int*)(ctrl);
    int*   s2t     = (int*)(ctrl + 16384);
    float* wgt     = (float*)(ctrl + 32768);
    float* wgtS    = (float*)(ctrl + 49152);
    int*   eS      = (int*)(ctrl + 65536);
    int*   offs    = (int*)(ctrl + 81920);
    int*   cursors = (int*)(ctrl + 81984);

    k_pre<<<5120, 256, 0, stream>>>(x, wr, w1, WT, w2, (unsigned short*)0, sel, wgt);
    k_prefix<<<1, 256, 0, stream>>>(sel, offs, cursors);
    k_scatter<<<T_TOK, 256, 0, stream>>>(x, sel, wgt, cursors, s2t, wgtS, eS, XS);
    k_ffn1<<<dim3(F_DIM / 128, T_TOK / 128, E_NUM), 256, 0, stream>>>(XS, WT, b1, HWS, offs);
    k_transpose<<<dim3(H_DIM / 64, F_DIM / 64, E_NUM), 256, 0, stream>>>(w2, WT, F_DIM, H_DIM);
    k_ffn2_direct<<<dim3(H_DIM / 128, T_TOK / 128, E_NUM), 256, 0, stream>>>(HWS, WT, b2, offs, s2t, wgtS, out);
  }
}

// Round 6
// 471.278 us; speedup vs baseline: 1.1385x; 1.0885x over previous
//
#include <hip/hip_runtime.h>
#include <math.h>

// Problem constants (B=2,S=2048 -> T=4096 tokens)
#define T_TOK 4096
#define H_DIM 1024
#define F_DIM 4096
#define E_NUM 8
#define BK 64
#define KSPLIT 4   // ffn2 split-K (fast path)
#define MT_MAX 40  // max split-K m-tiles: sum ceil(cnt_e/128) <= 32+7

typedef __attribute__((ext_vector_type(8))) short bhalf8_t;
typedef __attribute__((ext_vector_type(8))) unsigned short ushort8_t;
typedef __attribute__((ext_vector_type(4))) float f32x4_t;

// fp32 -> bf16 round-to-nearest-even
__device__ __forceinline__ unsigned short f2bf(float f) {
  unsigned int u = __float_as_uint(f);
  return (unsigned short)((u + 0x7fffu + ((u >> 16) & 1u)) >> 16);
}

// async global->LDS, 16B per lane. LDS dest = wave-uniform base + lane*16.
__device__ __forceinline__ void gload16(const void* g, void* l) {
  __builtin_amdgcn_global_load_lds(
      (const __attribute__((address_space(1))) unsigned int*)g,
      (__attribute__((address_space(3))) unsigned int*)l, 16, 0, 0);
}

// ---- fp32 [K][N] 64x64 tile -> bf16 [N][K] (proven pattern) ---------------
__device__ __forceinline__ void transpose_dev(const float* __restrict__ src,
                                              unsigned short* __restrict__ dst,
                                              int K, int N, int bx, int by, void* sm_) {
  float(*tile)[65] = (float(*)[65])sm_;  // 64x65 fp32, +1 pad
  const int n0 = bx * 64;
  const int k0 = by * 64;
  const int l = threadIdx.x;
  const int lr = l >> 4;          // 0..15 (k-row within pass)
  const int lc = (l & 15) * 4;    // 4-col group
#pragma unroll
  for (int i = 0; i < 64; i += 16) {
    const float4 v = *reinterpret_cast<const float4*>(&src[(size_t)(k0 + lr + i) * N + n0 + lc]);
    tile[lr + i][lc] = v.x;
    tile[lr + i][lc + 1] = v.y;
    tile[lr + i][lc + 2] = v.z;
    tile[lr + i][lc + 3] = v.w;
  }
  __syncthreads();
  const int kk = (l & 7) * 8;     // 8-k group
  const int nr = l >> 3;          // 0..31 (n-row within pass)
#pragma unroll
  for (int i = 0; i < 64; i += 32) {
    const int n = nr + i;
    ushort8_t o;
#pragma unroll
    for (int j = 0; j < 8; ++j) o[j] = f2bf(tile[kk + j][n]);
    *reinterpret_cast<ushort8_t*>(&dst[(size_t)(n0 + n) * K + k0 + kk]) = o;
  }
}

// ---- router body: fp64 accumulation protects argmax vs fp32 reference -----
__device__ __forceinline__ void router_body(const float* __restrict__ x,
                                            const float* __restrict__ wr,
                                            int t, int* __restrict__ sel,
                                            float* __restrict__ wgt) {
  const int lane = threadIdx.x & 63;
  const float* xr = x + (size_t)t * H_DIM;
  double acc[E_NUM] = {0, 0, 0, 0, 0, 0, 0, 0};
  for (int h = lane; h < H_DIM; h += 64) {
    const double xv = (double)xr[h];
    const float* w = wr + (size_t)h * E_NUM;
#pragma unroll
    for (int e = 0; e < E_NUM; ++e) acc[e] += xv * (double)w[e];
  }
#pragma unroll
  for (int e = 0; e < E_NUM; ++e) {
#pragma unroll
    for (int off = 32; off > 0; off >>= 1) acc[e] += __shfl_down(acc[e], off, 64);
  }
  if (lane == 0) {
    double m = acc[0];
    int a = 0;
#pragma unroll
    for (int e = 1; e < E_NUM; ++e)
      if (acc[e] > m) { m = acc[e]; a = e; }   // strict > == first-max (jnp.argmax)
    double s = 0.0;
#pragma unroll
    for (int e = 0; e < E_NUM; ++e) s += exp(acc[e] - m);
    sel[t] = a;
    wgt[t] = (float)(1.0 / s);  // softmax prob of the argmax
  }
}

// ---------------- kernel 1: w1 transpose + router (flat interleaved) -------
// 9216 blocks: id%9==8 -> router group (1024), else w1T tile (8192).
__global__ __launch_bounds__(256) void k_pre(const float* __restrict__ x,
                                             const float* __restrict__ wr,
                                             const float* __restrict__ w1,
                                             unsigned short* __restrict__ WT1,
                                             int* __restrict__ sel, float* __restrict__ wgt) {
  __shared__ __align__(16) char sm[64 * 65 * 4];
  const unsigned int id = blockIdx.x;
  const unsigned int r = id % 9u;
  const unsigned int q = id / 9u;  // 0..1023
  if (r < 8u) {  // w1 [E][H][F] -> WT1 [E][F][H]; 1024 tiles/expert
    const int tile = (int)(q * 8u + r);  // 0..8191
    const int e = tile >> 10;
    const int tt = tile & 1023;
    transpose_dev(w1 + (size_t)e * H_DIM * F_DIM, WT1 + (size_t)e * F_DIM * H_DIM,
                  H_DIM, F_DIM, tt & 63, tt >> 6, sm);
    return;
  }
  router_body(x, wr, (int)q * 4 + (threadIdx.x >> 6), sel, wgt);
}

// ---------------- kernel 2: prefix + FULL bucketing meta -------------------
// One 256-thread block: histogram -> exclusive prefix -> parallel s2t/wgtS/eS
// (slot order within an expert is arbitrary: per-token math is independent)
// -> split-K m-tile work table.
__global__ __launch_bounds__(256) void k_prefix(const int* __restrict__ sel,
                                                const float* __restrict__ wgt,
                                                int* __restrict__ offs,
                                                int* __restrict__ s2t,
                                                float* __restrict__ wgtS,
                                                int* __restrict__ eS,
                                                int* __restrict__ mtE,
                                                int* __restrict__ mtM,
                                                int* __restrict__ nmt) {
  __shared__ int h[E_NUM];
  __shared__ int cur[E_NUM];
  const int tid = threadIdx.x;
  if (tid < E_NUM) h[tid] = 0;
  __syncthreads();
  for (int i = tid; i < T_TOK; i += 256) atomicAdd(&h[sel[i]], 1);
  __syncthreads();
  if (tid == 0) {
    int s = 0, m = 0;
    for (int e = 0; e < E_NUM; ++e) {
      offs[e] = s;
      cur[e] = s;
      for (int m0 = 0; m0 < h[e]; m0 += 128) { mtE[m] = e; mtM[m] = m0; ++m; }
      s += h[e];
    }
    offs[E_NUM] = s;  // == T_TOK
    *nmt = m;
  }
  __syncthreads();
  for (int t = tid; t < T_TOK; t += 256) {
    const int e = sel[t];
    const int slot = atomicAdd(&cur[e], 1);
    s2t[slot] = t;
    wgtS[slot] = wgt[t];
    eS[slot] = e;
  }
}

// ---------------- kernel 3: pure gather-copy x rows -> bf16 Xs -------------
// 1024 blocks x 4 slots (one per wave). No atomics.
__global__ __launch_bounds__(256) void k_scatter(const float* __restrict__ x,
                                                 const int* __restrict__ s2t,
                                                 unsigned short* __restrict__ Xs) {
  const int wv = threadIdx.x >> 6;
  const int lane = threadIdx.x & 63;
  const int slot = blockIdx.x * 4 + wv;
  const int t = s2t[slot];
  const float4* xr = reinterpret_cast<const float4*>(x + (size_t)t * H_DIM);
  ushort4* xo = reinterpret_cast<ushort4*>(Xs + (size_t)slot * H_DIM);
#pragma unroll
  for (int kx = 0; kx < 4; ++kx) {
    const float4 v = xr[lane + kx * 64];
    ushort4 o;
    o.x = f2bf(v.x); o.y = f2bf(v.y); o.z = f2bf(v.z); o.w = f2bf(v.w);
    xo[lane + kx * 64] = o;
  }
}

// ---------------- kernel 4: FFN1 (128x128) || w2 transpose (proven) --------
// grid (64,32,8): x<32 -> ffn1 n-block; x>=32 -> w2T tile.
// Fallback launches (32,32,8) -> pure ffn1 (WT2 unused).
__global__ __launch_bounds__(256, 4) void k_mid(const unsigned short* __restrict__ Xs,
                                                const unsigned short* __restrict__ Wt,
                                                const float* __restrict__ b1,
                                                unsigned short* __restrict__ Hws,
                                                const int* __restrict__ offs,
                                                const float* __restrict__ w2,
                                                unsigned short* __restrict__ WT2) {
  __shared__ __align__(16) char sm[32768];
  if (blockIdx.x >= 32) {  // w2 [E][F][H] -> WT2 [E][H][F]
    const int id = blockIdx.y * 32 + (blockIdx.x - 32);  // 1024 tiles per expert
    transpose_dev(w2 + (size_t)blockIdx.z * F_DIM * H_DIM,
                  WT2 + (size_t)blockIdx.z * H_DIM * F_DIM,
                  F_DIM, H_DIM, id & 15, id >> 4, sm);
    return;
  }
  // ---- ffn1: h = relu(Xs @ w1[e] + b1[e]), 128m x 128n tile ----
  const int e = blockIdx.z;
  const int off = offs[e];
  const int cnt = offs[e + 1] - off;
  const int m0 = blockIdx.y * 128;
  if (m0 >= cnt) return;  // uniform early-exit
  const int n0 = blockIdx.x * 128;
  const int msize = cnt - m0;

  short* lA = (short*)sm;            // 16 KB
  short* lB = (short*)(sm + 16384);  // 16 KB

  const int tid = threadIdx.x;
  const int lane = tid & 63;
  const int wv = tid >> 6;         // 4 waves, 2x2 over 128x128
  const int wm = (wv >> 1) * 64;
  const int wn = (wv & 1) * 64;

  // staging: 8 rows/instr, 8 lanes/row, 16B chunk. XOR-swizzle the GLOBAL
  // chunk by dest row (&7) -> fragment ds_read_b128 measured conflict-free.
  const int sRow = lane >> 3;
  const int cc = lane & 7;
  const int gch = cc ^ sRow;

  const unsigned short* Abase = Xs + (size_t)off * H_DIM;
  const unsigned short* Bbase = Wt + (size_t)e * F_DIM * H_DIM + (size_t)n0 * H_DIM;

  f32x4_t acc[4][4];
#pragma unroll
  for (int i = 0; i < 4; ++i)
#pragma unroll
    for (int j = 0; j < 4; ++j) acc[i][j] = (f32x4_t){0.f, 0.f, 0.f, 0.f};

  const int q = lane >> 4;
  const int r16 = lane & 15;
  const int sw = r16 & 7;  // de-swizzle for fragment reads

  for (int k0 = 0; k0 < H_DIM; k0 += BK) {
    __syncthreads();
#pragma unroll
    for (int i = 0; i < 4; ++i) {
      const int g = wv * 4 + i;
      const int row = g * 8 + sRow;
      const int ar = (row < msize) ? row : 0;
      gload16(Abase + (size_t)(m0 + ar) * H_DIM + k0 + gch * 8, &lA[g * 8 * BK]);
      gload16(Bbase + (size_t)row * H_DIM + k0 + gch * 8, &lB[g * 8 * BK]);
    }
    __syncthreads();  // drains vmcnt for global_load_lds

#pragma unroll
    for (int step = 0; step < 2; ++step) {
      const int slot = (step * 4 + q) ^ sw;
      bhalf8_t af[4], bf[4];
#pragma unroll
      for (int mi = 0; mi < 4; ++mi)
        af[mi] = *reinterpret_cast<const bhalf8_t*>(&lA[(wm + mi * 16 + r16) * BK + slot * 8]);
#pragma unroll
      for (int ni = 0; ni < 4; ++ni)
        bf[ni] = *reinterpret_cast<const bhalf8_t*>(&lB[(wn + ni * 16 + r16) * BK + slot * 8]);
#pragma unroll
      for (int mi = 0; mi < 4; ++mi)
#pragma unroll
        for (int ni = 0; ni < 4; ++ni)
          acc[mi][ni] = __builtin_amdgcn_mfma_f32_16x16x32_bf16(af[mi], bf[ni], acc[mi][ni], 0, 0, 0);
    }
  }

  // epilogue: bias + relu -> bf16.  C/D map: row = quad*4+reg, col = lane&15
  const int c = lane & 15;
#pragma unroll
  for (int ni = 0; ni < 4; ++ni) {
    const int col = n0 + wn + ni * 16 + c;
    const float bias = b1[e * F_DIM + col];
#pragma unroll
    for (int mi = 0; mi < 4; ++mi) {
      const int rbase = wm + mi * 16 + q * 4;
#pragma unroll
      for (int r = 0; r < 4; ++r) {
        const int row = rbase + r;
        if (row < msize) {
          float v = acc[mi][ni][r] + bias;
          v = fmaxf(v, 0.0f);
          Hws[(size_t)(off + m0 + row) * F_DIM + col] = f2bf(v);
        }
      }
    }
  }
}

// ---- one FFN2 split-K work item (shared by compact + fallback kernels) ----
__device__ __forceinline__ void ffn2_item(const unsigned short* __restrict__ Hws,
                                          const unsigned short* __restrict__ Wt,
                                          const int* __restrict__ offs,
                                          float* __restrict__ P,
                                          int e, int m0, int n0, int ks) {
  __shared__ short lA[128 * BK];
  __shared__ short lB[128 * BK];
  const int off = offs[e];
  const int cnt = offs[e + 1] - off;
  const int msize = cnt - m0;
  const int kbeg = ks * (F_DIM / KSPLIT);
  const int kend = kbeg + (F_DIM / KSPLIT);

  const int tid = threadIdx.x;
  const int lane = tid & 63;
  const int wv = tid >> 6;
  const int wm = (wv >> 1) * 64;
  const int wn = (wv & 1) * 64;

  const int sRow = lane >> 3;
  const int cc = lane & 7;
  const int gch = cc ^ sRow;

  const unsigned short* Abase = Hws + (size_t)off * F_DIM;
  const unsigned short* Bbase = Wt + (size_t)e * H_DIM * F_DIM + (size_t)n0 * F_DIM;

  f32x4_t acc[4][4];
#pragma unroll
  for (int i = 0; i < 4; ++i)
#pragma unroll
    for (int j = 0; j < 4; ++j) acc[i][j] = (f32x4_t){0.f, 0.f, 0.f, 0.f};

  const int q = lane >> 4;
  const int r16 = lane & 15;
  const int sw = r16 & 7;

  for (int k0 = kbeg; k0 < kend; k0 += BK) {
    __syncthreads();
#pragma unroll
    for (int i = 0; i < 4; ++i) {
      const int g = wv * 4 + i;
      const int row = g * 8 + sRow;
      const int ar = (row < msize) ? row : 0;
      gload16(Abase + (size_t)(m0 + ar) * F_DIM + k0 + gch * 8, &lA[g * 8 * BK]);
      gload16(Bbase + (size_t)row * F_DIM + k0 + gch * 8, &lB[g * 8 * BK]);
    }
    __syncthreads();

#pragma unroll
    for (int step = 0; step < 2; ++step) {
      const int slot = (step * 4 + q) ^ sw;
      bhalf8_t af[4], bf[4];
#pragma unroll
      for (int mi = 0; mi < 4; ++mi)
        af[mi] = *reinterpret_cast<const bhalf8_t*>(&lA[(wm + mi * 16 + r16) * BK + slot * 8]);
#pragma unroll
      for (int ni = 0; ni < 4; ++ni)
        bf[ni] = *reinterpret_cast<const bhalf8_t*>(&lB[(wn + ni * 16 + r16) * BK + slot * 8]);
#pragma unroll
      for (int mi = 0; mi < 4; ++mi)
#pragma unroll
        for (int ni = 0; ni < 4; ++ni)
          acc[mi][ni] = __builtin_amdgcn_mfma_f32_16x16x32_bf16(af[mi], bf[ni], acc[mi][ni], 0, 0, 0);
    }
  }

  const int c = lane & 15;
  float* Pb = P + (size_t)ks * T_TOK * H_DIM;
#pragma unroll
  for (int mi = 0; mi < 4; ++mi) {
    const int rbase = wm + mi * 16 + q * 4;
#pragma unroll
    for (int r = 0; r < 4; ++r) {
      const int row = rbase + r;
      if (row >= msize) continue;
      float* prow = Pb + (size_t)(off + m0 + row) * H_DIM;
#pragma unroll
      for (int ni = 0; ni < 4; ++ni) prow[n0 + wn + ni * 16 + c] = acc[mi][ni][r];
    }
  }
}

// ---------------- kernel 5a: FFN2 split-K, compact grid via mt table -------
// grid (8, MT_MAX, KSPLIT); uniform early-exit on mt >= *nmt.
__global__ __launch_bounds__(256, 4) void k_ffn2_sk(const unsigned short* __restrict__ Hws,
                                                    const unsigned short* __restrict__ Wt,
                                                    const int* __restrict__ offs,
                                                    float* __restrict__ P,
                                                    const int* __restrict__ mtE,
                                                    const int* __restrict__ mtM,
                                                    const int* __restrict__ nmt) {
  const int mt = blockIdx.y;
  if (mt >= *nmt) return;
  ffn2_item(Hws, Wt, offs, P, mtE[mt], mtM[mt], blockIdx.x * 128, blockIdx.z);
}

// ---------------- kernel 5b: split-K reduce + bias + weight + scatter ------
// 1024 blocks x 4 sorted rows.
__global__ __launch_bounds__(256) void k_reduce(const float* __restrict__ P,
                                                const float* __restrict__ b2,
                                                const int* __restrict__ s2t,
                                                const int* __restrict__ eS,
                                                const float* __restrict__ wgtS,
                                                float* __restrict__ out) {
  const int i = threadIdx.x;  // 256 threads x float4 = 1024 = H
#pragma unroll 1
  for (int j = 0; j < 4; ++j) {
    const int srow = blockIdx.x * 4 + j;
    const int tok = s2t[srow];
    const int e = eS[srow];
    const float w = wgtS[srow];
    const size_t rowoff = (size_t)srow * H_DIM / 4 + i;
    const float4 p0 = reinterpret_cast<const float4*>(P)[rowoff];
    const float4 p1 = reinterpret_cast<const float4*>(P + (size_t)T_TOK * H_DIM)[rowoff];
    const float4 p2 = reinterpret_cast<const float4*>(P + (size_t)2 * T_TOK * H_DIM)[rowoff];
    const float4 p3 = reinterpret_cast<const float4*>(P + (size_t)3 * T_TOK * H_DIM)[rowoff];
    const float4 b = reinterpret_cast<const float4*>(b2 + (size_t)e * H_DIM)[i];
    float4 o;
    o.x = w * (p0.x + p1.x + p2.x + p3.x + b.x);
    o.y = w * (p0.y + p1.y + p2.y + p3.y + b.y);
    o.z = w * (p0.z + p1.z + p2.z + p3.z + b.z);
    o.w = w * (p0.w + p1.w + p2.w + p3.w + b.w);
    reinterpret_cast<float4*>(out + (size_t)tok * H_DIM)[i] = o;
  }
}

// ---------------- standalone transpose (fallback path only) ----------------
__global__ __launch_bounds__(256) void k_transpose(const float* __restrict__ in,
                                                   unsigned short* __restrict__ out,
                                                   int K, int N) {
  __shared__ __align__(16) char sm[64 * 65 * 4];
  transpose_dev(in + (size_t)blockIdx.z * K * N, out + (size_t)blockIdx.z * N * K,
                K, N, blockIdx.x, blockIdx.y, sm);
}

// ---------------- kernel 5c: FFN2 direct (fallback if ws too small) --------
__global__ __launch_bounds__(256, 4) void k_ffn2_direct(const unsigned short* __restrict__ Hws,
                                                        const unsigned short* __restrict__ Wt,
                                                        const float* __restrict__ b2,
                                                        const int* __restrict__ offs,
                                                        const int* __restrict__ s2t,
                                                        const float* __restrict__ wgtS,
                                                        float* __restrict__ out) {
  const int e = blockIdx.z;
  const int off = offs[e];
  const int cnt = offs[e + 1] - off;
  const int m0 = blockIdx.y * 128;
  if (m0 >= cnt) return;
  const int n0 = blockIdx.x * 128;
  const int msize = cnt - m0;

  __shared__ short lA[128 * BK];
  __shared__ short lB[128 * BK];

  const int tid = threadIdx.x;
  const int lane = tid & 63;
  const int wv = tid >> 6;
  const int wm = (wv >> 1) * 64;
  const int wn = (wv & 1) * 64;

  const int sRow = lane >> 3;
  const int cc = lane & 7;
  const int gch = cc ^ sRow;

  const unsigned short* Abase = Hws + (size_t)off * F_DIM;
  const unsigned short* Bbase = Wt + (size_t)e * H_DIM * F_DIM + (size_t)n0 * F_DIM;

  f32x4_t acc[4][4];
#pragma unroll
  for (int i = 0; i < 4; ++i)
#pragma unroll
    for (int j = 0; j < 4; ++j) acc[i][j] = (f32x4_t){0.f, 0.f, 0.f, 0.f};

  const int q = lane >> 4;
  const int r16 = lane & 15;
  const int sw = r16 & 7;

  for (int k0 = 0; k0 < F_DIM; k0 += BK) {
    __syncthreads();
#pragma unroll
    for (int i = 0; i < 4; ++i) {
      const int g = wv * 4 + i;
      const int row = g * 8 + sRow;
      const int ar = (row < msize) ? row : 0;
      gload16(Abase + (size_t)(m0 + ar) * F_DIM + k0 + gch * 8, &lA[g * 8 * BK]);
      gload16(Bbase + (size_t)row * F_DIM + k0 + gch * 8, &lB[g * 8 * BK]);
    }
    __syncthreads();

#pragma unroll
    for (int step = 0; step < 2; ++step) {
      const int slot = (step * 4 + q) ^ sw;
      bhalf8_t af[4], bf[4];
#pragma unroll
      for (int mi = 0; mi < 4; ++mi)
        af[mi] = *reinterpret_cast<const bhalf8_t*>(&lA[(wm + mi * 16 + r16) * BK + slot * 8]);
#pragma unroll
      for (int ni = 0; ni < 4; ++ni)
        bf[ni] = *reinterpret_cast<const bhalf8_t*>(&lB[(wn + ni * 16 + r16) * BK + slot * 8]);
#pragma unroll
      for (int mi = 0; mi < 4; ++mi)
#pragma unroll
        for (int ni = 0; ni < 4; ++ni)
          acc[mi][ni] = __builtin_amdgcn_mfma_f32_16x16x32_bf16(af[mi], bf[ni], acc[mi][ni], 0, 0, 0);
    }
  }

  const int c = lane & 15;
#pragma unroll
  for (int mi = 0; mi < 4; ++mi) {
    const int rbase = wm + mi * 16 + q * 4;
#pragma unroll
    for (int r = 0; r < 4; ++r) {
      const int row = rbase + r;
      if (row >= msize) continue;
      const int srow = off + m0 + row;
      const int tok = s2t[srow];
      const float w = wgtS[srow];
      float* orow = out + (size_t)tok * H_DIM;
#pragma unroll
      for (int ni = 0; ni < 4; ++ni) {
        const int col = n0 + wn + ni * 16 + c;
        orow[col] = w * (acc[mi][ni][r] + b2[e * H_DIM + col]);
      }
    }
  }
}

extern "C" void kernel_launch(void* const* d_in, const int* in_sizes, int n_in,
                              void* d_out, int out_size, void* d_ws, size_t ws_size,
                              hipStream_t stream) {
  const float* x  = (const float*)d_in[0];   // [2,2048,1024]
  const float* wr = (const float*)d_in[1];   // [1024,8]
  const float* w1 = (const float*)d_in[2];   // [8,1024,4096]
  const float* b1 = (const float*)d_in[3];   // [8,4096]
  const float* w2 = (const float*)d_in[4];   // [8,4096,1024]
  const float* b2 = (const float*)d_in[5];   // [8,1024]
  float* out = (float*)d_out;                // [2,2048,1024]

  char* ws = (char*)d_ws;
  // Fast path layout: WT1 64MB | WT2 64MB | XS 8MB | HWS 32MB | ctrl 96KB.
  // P (split-K partials, 64MB) aliases WT1: WT1's last reader (k_mid/ffn1)
  // completes before k_ffn2_sk writes P (stream order).
  const size_t NEED_FAST = 67108864ull * 2 + 8388608 + 33554432 + 98304;  // 176259072
  if (ws_size >= NEED_FAST) {
    unsigned short* WT1 = (unsigned short*)(ws);
    unsigned short* WT2 = (unsigned short*)(ws + 67108864);
    unsigned short* XS  = (unsigned short*)(ws + 134217728);
    unsigned short* HWS = (unsigned short*)(ws + 142606336);
    char* ctrl = ws + 176160768;
    int*   sel     = (int*)(ctrl);
    int*   s2t     = (int*)(ctrl + 16384);
    float* wgt     = (float*)(ctrl + 32768);
    float* wgtS    = (float*)(ctrl + 49152);
    int*   eS      = (int*)(ctrl + 65536);
    int*   offs    = (int*)(ctrl + 81920);
    int*   mtE     = (int*)(ctrl + 82048);
    int*   mtM     = (int*)(ctrl + 82304);
    int*   nmt     = (int*)(ctrl + 82560);
    float* P = (float*)ws;  // alias WT1 (exactly 64MB for KSPLIT=4)

    k_pre<<<9216, 256, 0, stream>>>(x, wr, w1, WT1, sel, wgt);
    k_prefix<<<1, 256, 0, stream>>>(sel, wgt, offs, s2t, wgtS, eS, mtE, mtM, nmt);
    k_scatter<<<T_TOK / 4, 256, 0, stream>>>(x, s2t, XS);
    k_mid<<<dim3(64, 32, 8), 256, 0, stream>>>(XS, WT1, b1, HWS, offs, w2, WT2);
    k_ffn2_sk<<<dim3(H_DIM / 128, MT_MAX, KSPLIT), 256, 0, stream>>>(HWS, WT2, offs, P, mtE, mtM, nmt);
    k_reduce<<<T_TOK / 4, 256, 0, stream>>>(P, b2, s2t, eS, wgtS, out);
  } else {
    // Fallback: single WT buffer, sequential transposes, direct ffn2.
    unsigned short* WT  = (unsigned short*)(ws);
    unsigned short* XS  = (unsigned short*)(ws + 67108864);
    unsigned short* HWS = (unsigned short*)(ws + 75497472);
    char* ctrl = ws + 109051904;
    int*   sel     = (int*)(ctrl);
    int*   s2t     = (int*)(ctrl + 16384);
    float* wgt     = (float*)(ctrl + 32768);
    float* wgtS    = (float*)(ctrl + 49152);
    int*   eS      = (int*)(ctrl + 65536);
    int*   offs    = (int*)(ctrl + 81920);
    int*   mtE     = (int*)(ctrl + 82048);
    int*   mtM     = (int*)(ctrl + 82304);
    int*   nmt     = (int*)(ctrl + 82560);

    k_pre<<<9216, 256, 0, stream>>>(x, wr, w1, WT, sel, wgt);
    k_prefix<<<1, 256, 0, stream>>>(sel, wgt, offs, s2t, wgtS, eS, mtE, mtM, nmt);
    k_scatter<<<T_TOK / 4, 256, 0, stream>>>(x, s2t, XS);
    k_mid<<<dim3(32, 32, 8), 256, 0, stream>>>(XS, WT, b1, HWS, offs, w2, (unsigned short*)0);
    k_transpose<<<dim3(H_DIM / 64, F_DIM / 64, E_NUM), 256, 0, stream>>>(w2, WT, F_DIM, H_DIM);
    k_ffn2_direct<<<dim3(H_DIM / 128, T_TOK / 128, E_NUM), 256, 0, stream>>>(HWS, WT, b2, offs, s2t, wgtS, out);
  }
}